// Round 5
// baseline (360.942 us; speedup 1.0000x reference)
//
#include <hip/hip_runtime.h>
#include <hip/hip_fp16.h>
#include <math.h>

// B=8, S=1024, D=256, H=8, DH=32
constexpr int Bsz = 8, Ssz = 1024, Dsz = 256, Hn = 8, DHn = 32;
// attn LDS: 16 rows x 1024 fp16, XOR-swizzled (no pad) = 32 KB -> 5 blocks/CU
constexpr int SST = 1024;

typedef __attribute__((ext_vector_type(8))) short short8;
typedef __attribute__((ext_vector_type(4))) float floatx4;
typedef __attribute__((ext_vector_type(2))) float floatx2;

#define DEV static __device__ __forceinline__

// swizzle: XOR row bits into col bits 3..5 (8-short granule). Keeps 8-short
// blocks contiguous (phase1/3 16B accesses) and 4-short blocks contiguous
// (phase2 8B accesses); breaks the row-stride bank aliasing of SST=1024.
DEV int swz(int row, int col) { return col ^ ((row & 7) << 3); }

DEV short f2bf(float f) {  // fp32 -> bf16 RNE
  union { float f; unsigned u; } x; x.f = f;
  return (short)((x.u + 0x7fffu + ((x.u >> 16) & 1u)) >> 16);
}
DEV short f2h(float f) {
  __half h = __float2half(f);
  return *(short*)&h;
}
DEV unsigned bfpk(float lo, float hi) {  // v_cvt_pk_bf16_f32: {hi,lo} -> 2xbf16
  unsigned r;
  asm("v_cvt_pk_bf16_f32 %0, %1, %2" : "=v"(r) : "v"(lo), "v"(hi));
  return r;
}
DEV float ex2(float x) {  // raw v_exp_f32 (2^x)
#if __has_builtin(__builtin_amdgcn_exp2f)
  return __builtin_amdgcn_exp2f(x);
#else
  return __expf(x * 0.69314718055994531f);
#endif
}
DEV float wsum(float v) {
#pragma unroll
  for (int off = 32; off > 0; off >>= 1) v += __shfl_xor(v, off, 64);
  return v;
}

// ============ W pre-convert: fp32 row-major -> bf16 MFMA B-frag order =======
// layout: [kblk(8)][ntile(16)][lane(64)][8 bf16]; element =
//   W[ntile*16 + (lane&15)][kblk*32 + (lane>>4)*8 + j]
__global__ __launch_bounds__(256) void cvt_wfrag(const float* __restrict__ Wq,
                                                 const float* __restrict__ Wv,
                                                 const float* __restrict__ Wo,
                                                 short* __restrict__ dst) {
  const int which = blockIdx.y;
  const float* W = (which == 0) ? Wq : (which == 1) ? Wv : Wo;
  const int t = blockIdx.x * 256 + threadIdx.x;  // 0..8191
  const int ln = t & 63, nt = (t >> 6) & 15, kblk = t >> 10;
  const float* src = W + (size_t)(nt * 16 + (ln & 15)) * 256 + kblk * 32 + (ln >> 4) * 8;
  const float4 a = *(const float4*)src;
  const float4 b = *(const float4*)(src + 4);
  const float tmp[8] = {a.x, a.y, a.z, a.w, b.x, b.y, b.z, b.w};
  short8 s;
#pragma unroll
  for (int j = 0; j < 8; ++j) s[j] = f2bf(tmp[j]);
  *(short8*)(dst + ((size_t)which << 16) + (size_t)t * 8) = s;
}

// ============ projections: 32 rows x full N=256 per block ==================
// Xs: 32x80 bf16, granule-XOR swizzled. Wave w owns n-range [w*64, w*64+64).
__global__ __launch_bounds__(256, 4) void proj_qkv2(
    const float* __restrict__ qi, const float* __restrict__ ki, const float* __restrict__ vi,
    const short* __restrict__ Wfrag, const float* __restrict__ bq, const float* __restrict__ bv,
    short* __restrict__ qh, short* __restrict__ kh, short* __restrict__ vt) {
  __shared__ short Xs[32 * 80];
  const int which = blockIdx.y;
  const float* X = (which == 0) ? qi : (which == 1) ? ki : vi;
  const short* Wf = Wfrag + ((which == 2) ? (1 << 16) : 0);
  const float* bias = (which == 2) ? bv : bq;
  const int tid = threadIdx.x, ln = tid & 63, w = tid >> 6;
  const int lm = ln & 15, qq = ln >> 4;
  const int bm = blockIdx.x;  // 256 blocks of 32 rows
  const float* Xb = X + (size_t)bm * 32 * 256;
  floatx4 acc[2][4] = {};

  for (int k0 = 0; k0 < 4; ++k0) {
    __syncthreads();
    {
      const int row = tid >> 3, cg = tid & 7;
#pragma unroll
      for (int i = 0; i < 2; ++i) {
        const float4 f = *(const float4*)(Xb + (size_t)row * 256 + k0 * 64 + cg * 8 + i * 4);
        short4 s; s.x = f2bf(f.x); s.y = f2bf(f.y); s.z = f2bf(f.z); s.w = f2bf(f.w);
        *(short4*)(Xs + row * 80 + (cg ^ (row & 7)) * 8 + i * 4) = s;
      }
    }
    __syncthreads();
#pragma unroll
    for (int ks = 0; ks < 2; ++ks) {
      const int kblk = k0 * 2 + ks;
      short8 a[2], b[4];
#pragma unroll
      for (int mt = 0; mt < 2; ++mt) {
        const int row = mt * 16 + lm;
        a[mt] = *(const short8*)(Xs + row * 80 + (((ks * 4 + qq)) ^ (row & 7)) * 8);
      }
#pragma unroll
      for (int nt = 0; nt < 4; ++nt)
        b[nt] = *(const short8*)(Wf + ((size_t)(kblk * 16 + w * 4 + nt) * 64 + ln) * 8);
#pragma unroll
      for (int mt = 0; mt < 2; ++mt)
#pragma unroll
        for (int nt = 0; nt < 4; ++nt)
          acc[mt][nt] = __builtin_amdgcn_mfma_f32_16x16x32_bf16(a[mt], b[nt], acc[mt][nt], 0, 0, 0);
    }
  }

#pragma unroll
  for (int mt = 0; mt < 2; ++mt) {
#pragma unroll
    for (int nt = 0; nt < 4; ++nt) {
      const int n = w * 64 + nt * 16 + lm;
      const float bval = bias[n];
      const int m0 = bm * 32 + mt * 16 + qq * 4;
      const int h = n >> 5, dh = n & 31;
      if (which <= 1) {  // head-split [B,H,S,DH]
        short* dst = (which == 0) ? qh : kh;
#pragma unroll
        for (int r = 0; r < 4; ++r) {
          const int m = m0 + r, b_ = m >> 10, s = m & 1023;
          dst[(((size_t)(b_ * Hn + h) << 10) + s) * DHn + dh] = f2bf(acc[mt][nt][r] + bval);
        }
      } else {  // V^T [B,H,DH,S]
        const int b_ = m0 >> 10, s0 = m0 & 1023;
        short4 pk;
        pk.x = f2bf(acc[mt][nt][0] + bval);
        pk.y = f2bf(acc[mt][nt][1] + bval);
        pk.z = f2bf(acc[mt][nt][2] + bval);
        pk.w = f2bf(acc[mt][nt][3] + bval);
        *(short4*)(vt + ((size_t)((b_ * Hn + h) * DHn + dh) << 10) + s0) = pk;
      }
    }
  }
}

__global__ __launch_bounds__(256, 4) void proj_out2(
    const short* __restrict__ oc, const short* __restrict__ Wfrag,
    const float* __restrict__ bo, float* __restrict__ out) {
  __shared__ short Xs[32 * 80];
  const short* Wf = Wfrag + (2 << 16);
  const int tid = threadIdx.x, ln = tid & 63, w = tid >> 6;
  const int lm = ln & 15, qq = ln >> 4;
  const int bm = blockIdx.x;
  const short* Xb = oc + (size_t)bm * 32 * 256;
  floatx4 acc[2][4] = {};

  for (int k0 = 0; k0 < 4; ++k0) {
    __syncthreads();
    {
      const int row = tid >> 3, cg = tid & 7;
      const short8 s = *(const short8*)(Xb + (size_t)row * 256 + k0 * 64 + cg * 8);
      *(short8*)(Xs + row * 80 + (cg ^ (row & 7)) * 8) = s;
    }
    __syncthreads();
#pragma unroll
    for (int ks = 0; ks < 2; ++ks) {
      const int kblk = k0 * 2 + ks;
      short8 a[2], b[4];
#pragma unroll
      for (int mt = 0; mt < 2; ++mt) {
        const int row = mt * 16 + lm;
        a[mt] = *(const short8*)(Xs + row * 80 + (((ks * 4 + qq)) ^ (row & 7)) * 8);
      }
#pragma unroll
      for (int nt = 0; nt < 4; ++nt)
        b[nt] = *(const short8*)(Wf + ((size_t)(kblk * 16 + w * 4 + nt) * 64 + ln) * 8);
#pragma unroll
      for (int mt = 0; mt < 2; ++mt)
#pragma unroll
        for (int nt = 0; nt < 4; ++nt)
          acc[mt][nt] = __builtin_amdgcn_mfma_f32_16x16x32_bf16(a[mt], b[nt], acc[mt][nt], 0, 0, 0);
    }
  }
#pragma unroll
  for (int mt = 0; mt < 2; ++mt)
#pragma unroll
    for (int nt = 0; nt < 4; ++nt) {
      const int n = w * 64 + nt * 16 + lm;
      const float bval = bo[n];
      const int m0 = bm * 32 + mt * 16 + qq * 4;
#pragma unroll
      for (int r = 0; r < 4; ++r)
        __builtin_nontemporal_store(acc[mt][nt][r] + bval, out + (size_t)(m0 + r) * 256 + n);
    }
}

// ======================= fused attention ===================================
// phase2 v6: occupancy-oriented.
//  - LDS row stride 1024 (no pad) + XOR swizzle -> 32 KB/block, 5 blocks/CU.
//  - no sv register arrays: pass B reloads t from LDS (frees 16 VGPRs at
//    NP=4 so the kernel fits the 5-waves/EU VGPR cap).
//  - zero tail of scores rows folded into the store loop (p always to 4).
template <int NP>
DEV void phase2(short* ss, float* shead, int row0, int w, int ln, float gsq) {
  const int c0 = ln * 4;
  for (int rr = 0; rr < 4; ++rr) {
    const int m = w * 4 + rr;
    const int irow = row0 + m;
    short* srow = ss + m * SST;

    floatx2 e01[NP], e23[NP];
    float ls[NP];

    // pass A: load t (= score*log2e) from fp16 LDS, e = 2^t (diag-masked),
    // per-lane chunk sums.
#pragma unroll
    for (int p = 0; p < NP; ++p) {
      const uint2 u = *(const uint2*)(srow + swz(m, p * 256 + c0));
      const float2 f0 = __half22float2(*(const __half2*)&u.x);
      const float2 f1 = __half22float2(*(const __half2*)&u.y);
      float e0 = ex2(f0.x), e1 = ex2(f0.y), e2 = ex2(f1.x), e3 = ex2(f1.y);
      if (p == NP - 1) {  // only diagonal chunk can be masked
        const int cb = p * 256 + c0;
        e0 = (cb + 0 <= irow) ? e0 : 0.f;
        e1 = (cb + 1 <= irow) ? e1 : 0.f;
        e2 = (cb + 2 <= irow) ? e2 : 0.f;
        e3 = (cb + 3 <= irow) ? e3 : 0.f;
      }
      e01[p].x = e0; e01[p].y = e1; e23[p].x = e2; e23[p].y = e3;
      ls[p] = (e0 + e1) + (e2 + e3);
    }

    // NP independent wave-scans in lockstep, then serial prefix of totals.
    float incl[NP];
#pragma unroll
    for (int p = 0; p < NP; ++p) incl[p] = ls[p];
#pragma unroll
    for (int off = 1; off < 64; off <<= 1) {
#pragma unroll
      for (int p = 0; p < NP; ++p) {
        const float y = __shfl_up(incl[p], off, 64);
        if (ln >= off) incl[p] += y;
      }
    }
    float excl[NP], Z = 0.f;
#pragma unroll
    for (int p = 0; p < NP; ++p) {
      excl[p] = Z + incl[p] - ls[p];
      Z += __shfl(incl[p], 63, 64);
    }
    const float invZ = 1.f / Z;

    // pass B: distance decay + second (unnormalized) softmax numerator.
    // t reloaded from LDS (saves 16 VGPRs at NP=4).
    float ls2 = 0.f;
#pragma unroll
    for (int p = 0; p < NP; ++p) {
      const uint2 u = *(const uint2*)(srow + swz(m, p * 256 + c0));
      const float2 f0 = __half22float2(*(const __half2*)&u.x);
      const float2 f1 = __half22float2(*(const __half2*)&u.y);
      const float tv[4] = {f0.x, f0.y, f1.x, f1.y};
      const float ev[4] = {e01[p].x, e01[p].y, e23[p].x, e23[p].y};
      float cum = excl[p];
      // pos' = g^2 * (irow - c), maintained incrementally
      float pos = gsq * (float)(irow - (p * 256 + c0));
      float xv[4];
#pragma unroll
      for (int j = 0; j < 4; ++j) {
        cum += ev[j];
        const float tail = 1.f - cum * invZ;      // (Z-cum)/Z
        const float d = sqrtf(__builtin_fabsf(tail * pos));
        const float eff = fmaxf(ex2(-d), 1e-5f);  // 2^(g*dist)
        float x = ex2(tv[j] * eff);
        if (p == NP - 1)
          x = (p * 256 + c0 + j <= irow) ? x : 0.f;
        xv[j] = x;
        ls2 += x;
        pos -= gsq;
      }
      e01[p].x = xv[0]; e01[p].y = xv[1];
      e23[p].x = xv[2]; e23[p].y = xv[3];
    }
    const float i2 = 1.f / wsum(ls2);

    float* grow = shead + (size_t)irow * Ssz;
    const floatx4 z4 = {0.f, 0.f, 0.f, 0.f};
#pragma unroll
    for (int p = 0; p < 4; ++p) {
      if (p >= NP) {  // masked tail: exact zeros
        __builtin_nontemporal_store(z4, (floatx4*)(grow + p * 256 + c0));
        continue;
      }
      floatx4 o;
      o.x = e01[p].x * i2; o.y = e01[p].y * i2;
      o.z = e23[p].x * i2; o.w = e23[p].y * i2;
      __builtin_nontemporal_store(o, (floatx4*)(grow + p * 256 + c0));
      uint2 pk;
      pk.x = bfpk(o.x, o.y);
      pk.y = bfpk(o.z, o.w);
      *(uint2*)(srow + swz(m, p * 256 + c0)) = pk;
    }
  }
}

__global__ __launch_bounds__(256, 5) void attn_kernel(
    const short* __restrict__ qh, const short* __restrict__ kh,
    const short* __restrict__ vt, const float* __restrict__ gammas,
    float* __restrict__ scores_out, short* __restrict__ oc) {
  __shared__ short ss[16 * SST];  // 32 KB exactly -> 5 blocks/CU

  const int tid = threadIdx.x, ln = tid & 63, w = tid >> 6;
  const int lm = ln & 15, qq = ln >> 4;
  const int bh = blockIdx.x >> 6;
  const int row0 = (63 - (blockIdx.x & 63)) << 4;  // heavy tiles first
  const int h = bh & 7, b = bh >> 3;
  // scale * log2(e): LDS scores hold t = s*log2e so exps are raw v_exp_f32
  const float scaleL2e = 0.17677669529663687f * 1.4426950408889634f;
  const float g2 = -fabsf(gammas[h]) * 1.4426950408889634f;
  const float gsq = g2 * g2;  // eff = 2^(-sqrt(gsq*tail*pos))

  const short* qhead = qh + (size_t)bh * Ssz * DHn;
  const short* khead = kh + (size_t)bh * Ssz * DHn;
  const short* vhead = vt + (size_t)bh * DHn * Ssz;
  float* shead = scores_out + ((size_t)bh << 20);

  const short8 qa = *(const short8*)(qhead + (row0 + lm) * DHn + qq * 8);

  // phase 1: QK^T -> fp16 t-values in LDS (causal tiles only)
  const int ntile = (row0 >> 4) + 1;
  for (int t = w; t < ntile; t += 4) {
    const int n0 = t * 16;
    const short8 kb = *(const short8*)(khead + (n0 + lm) * DHn + qq * 8);
    floatx4 c = {0.f, 0.f, 0.f, 0.f};
    c = __builtin_amdgcn_mfma_f32_16x16x32_bf16(qa, kb, c, 0, 0, 0);
#pragma unroll
    for (int r = 0; r < 4; ++r) {
      const int row = qq * 4 + r;
      ss[row * SST + swz(row, n0 + lm)] = f2h(c[r] * scaleL2e);
    }
  }
  __syncthreads();

  // phase 2 (includes zero tail of scores rows)
  const int NPc = (row0 >> 8) + 1;
  switch (NPc) {
    case 1: phase2<1>(ss, shead, row0, w, ln, gsq); break;
    case 2: phase2<2>(ss, shead, row0, w, ln, gsq); break;
    case 3: phase2<3>(ss, shead, row0, w, ln, gsq); break;
    default: phase2<4>(ss, shead, row0, w, ln, gsq); break;
  }
  __syncthreads();

  // phase 3: PV via MFMA, two accumulator sets to halve the dep chain
  floatx4 o0 = {0.f, 0.f, 0.f, 0.f}, o1 = {0.f, 0.f, 0.f, 0.f};
  floatx4 p0 = {0.f, 0.f, 0.f, 0.f}, p1 = {0.f, 0.f, 0.f, 0.f};
  const int nkt = (row0 >> 5) + 1;
  int kt = w;
  for (; kt + 4 < nkt; kt += 8) {
    {
      const int k0 = kt * 32;
      const short8 av = *(const short8*)(ss + lm * SST + swz(lm, k0 + qq * 8));
      const short8 b0 = *(const short8*)(vhead + (lm << 10) + k0 + qq * 8);
      const short8 b1 = *(const short8*)(vhead + ((16 + lm) << 10) + k0 + qq * 8);
      o0 = __builtin_amdgcn_mfma_f32_16x16x32_bf16(av, b0, o0, 0, 0, 0);
      o1 = __builtin_amdgcn_mfma_f32_16x16x32_bf16(av, b1, o1, 0, 0, 0);
    }
    {
      const int k0 = (kt + 4) * 32;
      const short8 av = *(const short8*)(ss + lm * SST + swz(lm, k0 + qq * 8));
      const short8 b0 = *(const short8*)(vhead + (lm << 10) + k0 + qq * 8);
      const short8 b1 = *(const short8*)(vhead + ((16 + lm) << 10) + k0 + qq * 8);
      p0 = __builtin_amdgcn_mfma_f32_16x16x32_bf16(av, b0, p0, 0, 0, 0);
      p1 = __builtin_amdgcn_mfma_f32_16x16x32_bf16(av, b1, p1, 0, 0, 0);
    }
  }
  if (kt < nkt) {
    const int k0 = kt * 32;
    const short8 av = *(const short8*)(ss + lm * SST + swz(lm, k0 + qq * 8));
    const short8 b0 = *(const short8*)(vhead + (lm << 10) + k0 + qq * 8);
    const short8 b1 = *(const short8*)(vhead + ((16 + lm) << 10) + k0 + qq * 8);
    o0 = __builtin_amdgcn_mfma_f32_16x16x32_bf16(av, b0, o0, 0, 0, 0);
    o1 = __builtin_amdgcn_mfma_f32_16x16x32_bf16(av, b1, o1, 0, 0, 0);
  }
  o0 = o0 + p0;
  o1 = o1 + p1;
  __syncthreads();
  float* red = (float*)ss;  // alias, 8 KB
#pragma unroll
  for (int r = 0; r < 4; ++r) {
    red[(w * 16 + qq * 4 + r) * 32 + lm] = o0[r];
    red[(w * 16 + qq * 4 + r) * 32 + 16 + lm] = o1[r];
  }
  __syncthreads();
  {
    const int m = tid >> 4, n = tid & 15;
    float a0 = 0.f, a1 = 0.f;
#pragma unroll
    for (int wv = 0; wv < 4; ++wv) {
      a0 += red[(wv * 16 + m) * 32 + n];
      a1 += red[(wv * 16 + m) * 32 + 16 + n];
    }
    const size_t row = ((size_t)b << 10) + row0 + m;
    oc[row * Dsz + h * DHn + n] = f2bf(a0);
    oc[row * Dsz + h * DHn + 16 + n] = f2bf(a1);
  }
}

// ---------------- launch ---------------------------------------------------
extern "C" void kernel_launch(void* const* d_in, const int* in_sizes, int n_in,
                              void* d_out, int out_size, void* d_ws, size_t ws_size,
                              hipStream_t stream) {
  const float* q  = (const float*)d_in[0];
  const float* k  = (const float*)d_in[1];
  const float* v  = (const float*)d_in[2];
  const float* Wq = (const float*)d_in[4];
  const float* bq = (const float*)d_in[5];
  const float* Wv = (const float*)d_in[6];
  const float* bv = (const float*)d_in[7];
  const float* Wo = (const float*)d_in[8];
  const float* bo = (const float*)d_in[9];
  const float* gm = (const float*)d_in[10];

  float* out    = (float*)d_out;                  // [B,S,D] fp32
  float* scores = out + (size_t)Bsz * Ssz * Dsz;  // [B,H,S,S] fp32

  const size_t Q = (size_t)Bsz * Hn * Ssz * DHn;
  short* qh = (short*)d_ws;        // bf16 [B,H,S,DH]
  short* kh = qh + Q;
  short* vt = kh + Q;              // bf16 [B,H,DH,S]
  short* oc = vt + Q;              // bf16 [B,S,D]
  short* Wf = oc + Q;              // bf16 frag-order weights, 3 x 65536

  const dim3 blk(256);
  hipLaunchKernelGGL(cvt_wfrag, dim3(32, 3), blk, 0, stream, Wq, Wv, Wo, Wf);
  hipLaunchKernelGGL(proj_qkv2, dim3(256, 3), blk, 0, stream,
                     q, k, v, Wf, bq, bv, qh, kh, vt);
  hipLaunchKernelGGL(attn_kernel, dim3(Bsz * Hn * (Ssz / 16)), blk, 0, stream,
                     qh, kh, vt, gm, scores, oc);
  hipLaunchKernelGGL(proj_out2, dim3(256), blk, 0, stream, oc, Wf, bo, out);
}

// Round 6
// 358.321 us; speedup vs baseline: 1.0073x; 1.0073x over previous
//
#include <hip/hip_runtime.h>
#include <hip/hip_fp16.h>
#include <math.h>

// B=8, S=1024, D=256, H=8, DH=32
constexpr int Bsz = 8, Ssz = 1024, Dsz = 256, Hn = 8, DHn = 32;
constexpr int SST = 1160;  // attn LDS row stride in shorts (padded, conflict-free)

typedef __attribute__((ext_vector_type(8))) short short8;
typedef __attribute__((ext_vector_type(4))) float floatx4;

#define DEV static __device__ __forceinline__

DEV short f2bf(float f) {  // fp32 -> bf16 RNE
  union { float f; unsigned u; } x; x.f = f;
  return (short)((x.u + 0x7fffu + ((x.u >> 16) & 1u)) >> 16);
}
DEV short f2h(float f) {
  __half h = __float2half(f);
  return *(short*)&h;
}
DEV unsigned bfpk(float lo, float hi) {  // v_cvt_pk_bf16_f32: {hi,lo} -> 2xbf16
  unsigned r;
  asm("v_cvt_pk_bf16_f32 %0, %1, %2" : "=v"(r) : "v"(lo), "v"(hi));
  return r;
}
DEV float ex2(float x) {  // raw v_exp_f32 (2^x)
#if __has_builtin(__builtin_amdgcn_exp2f)
  return __builtin_amdgcn_exp2f(x);
#else
  return __expf(x * 0.69314718055994531f);
#endif
}
DEV float wsum(float v) {
#pragma unroll
  for (int off = 32; off > 0; off >>= 1) v += __shfl_xor(v, off, 64);
  return v;
}

// ============ W pre-convert: fp32 row-major -> bf16 MFMA B-frag order =======
// layout: [kblk(8)][ntile(16)][lane(64)][8 bf16]; element =
//   W[ntile*16 + (lane&15)][kblk*32 + (lane>>4)*8 + j]
__global__ __launch_bounds__(256) void cvt_wfrag(const float* __restrict__ Wq,
                                                 const float* __restrict__ Wv,
                                                 const float* __restrict__ Wo,
                                                 short* __restrict__ dst) {
  const int which = blockIdx.y;
  const float* W = (which == 0) ? Wq : (which == 1) ? Wv : Wo;
  const int t = blockIdx.x * 256 + threadIdx.x;  // 0..8191
  const int ln = t & 63, nt = (t >> 6) & 15, kblk = t >> 10;
  const float* src = W + (size_t)(nt * 16 + (ln & 15)) * 256 + kblk * 32 + (ln >> 4) * 8;
  const float4 a = *(const float4*)src;
  const float4 b = *(const float4*)(src + 4);
  const float tmp[8] = {a.x, a.y, a.z, a.w, b.x, b.y, b.z, b.w};
  short8 s;
#pragma unroll
  for (int j = 0; j < 8; ++j) s[j] = f2bf(tmp[j]);
  *(short8*)(dst + ((size_t)which << 16) + (size_t)t * 8) = s;
}

// ============ projections: 32 rows x full N=256 per block ==================
// Xs: 32x80 bf16, granule-XOR swizzled. Wave w owns n-range [w*64, w*64+64).
__global__ __launch_bounds__(256, 4) void proj_qkv2(
    const float* __restrict__ qi, const float* __restrict__ ki, const float* __restrict__ vi,
    const short* __restrict__ Wfrag, const float* __restrict__ bq, const float* __restrict__ bv,
    short* __restrict__ qh, short* __restrict__ kh, short* __restrict__ vt) {
  __shared__ short Xs[32 * 80];
  const int which = blockIdx.y;
  const float* X = (which == 0) ? qi : (which == 1) ? ki : vi;
  const short* Wf = Wfrag + ((which == 2) ? (1 << 16) : 0);
  const float* bias = (which == 2) ? bv : bq;
  const int tid = threadIdx.x, ln = tid & 63, w = tid >> 6;
  const int lm = ln & 15, qq = ln >> 4;
  const int bm = blockIdx.x;  // 256 blocks of 32 rows
  const float* Xb = X + (size_t)bm * 32 * 256;
  floatx4 acc[2][4] = {};

  for (int k0 = 0; k0 < 4; ++k0) {
    __syncthreads();
    {
      const int row = tid >> 3, cg = tid & 7;
#pragma unroll
      for (int i = 0; i < 2; ++i) {
        const float4 f = *(const float4*)(Xb + (size_t)row * 256 + k0 * 64 + cg * 8 + i * 4);
        short4 s; s.x = f2bf(f.x); s.y = f2bf(f.y); s.z = f2bf(f.z); s.w = f2bf(f.w);
        *(short4*)(Xs + row * 80 + (cg ^ (row & 7)) * 8 + i * 4) = s;
      }
    }
    __syncthreads();
#pragma unroll
    for (int ks = 0; ks < 2; ++ks) {
      const int kblk = k0 * 2 + ks;
      short8 a[2], b[4];
#pragma unroll
      for (int mt = 0; mt < 2; ++mt) {
        const int row = mt * 16 + lm;
        a[mt] = *(const short8*)(Xs + row * 80 + (((ks * 4 + qq)) ^ (row & 7)) * 8);
      }
#pragma unroll
      for (int nt = 0; nt < 4; ++nt)
        b[nt] = *(const short8*)(Wf + ((size_t)(kblk * 16 + w * 4 + nt) * 64 + ln) * 8);
#pragma unroll
      for (int mt = 0; mt < 2; ++mt)
#pragma unroll
        for (int nt = 0; nt < 4; ++nt)
          acc[mt][nt] = __builtin_amdgcn_mfma_f32_16x16x32_bf16(a[mt], b[nt], acc[mt][nt], 0, 0, 0);
    }
  }

#pragma unroll
  for (int mt = 0; mt < 2; ++mt) {
#pragma unroll
    for (int nt = 0; nt < 4; ++nt) {
      const int n = w * 64 + nt * 16 + lm;
      const float bval = bias[n];
      const int m0 = bm * 32 + mt * 16 + qq * 4;
      const int h = n >> 5, dh = n & 31;
      if (which <= 1) {  // head-split [B,H,S,DH]
        short* dst = (which == 0) ? qh : kh;
#pragma unroll
        for (int r = 0; r < 4; ++r) {
          const int m = m0 + r, b_ = m >> 10, s = m & 1023;
          dst[(((size_t)(b_ * Hn + h) << 10) + s) * DHn + dh] = f2bf(acc[mt][nt][r] + bval);
        }
      } else {  // V^T [B,H,DH,S]
        const int b_ = m0 >> 10, s0 = m0 & 1023;
        short4 pk;
        pk.x = f2bf(acc[mt][nt][0] + bval);
        pk.y = f2bf(acc[mt][nt][1] + bval);
        pk.z = f2bf(acc[mt][nt][2] + bval);
        pk.w = f2bf(acc[mt][nt][3] + bval);
        *(short4*)(vt + ((size_t)((b_ * Hn + h) * DHn + dh) << 10) + s0) = pk;
      }
    }
  }
}

__global__ __launch_bounds__(256, 4) void proj_out2(
    const short* __restrict__ oc, const short* __restrict__ Wfrag,
    const float* __restrict__ bo, float* __restrict__ out) {
  __shared__ short Xs[32 * 80];
  const short* Wf = Wfrag + (2 << 16);
  const int tid = threadIdx.x, ln = tid & 63, w = tid >> 6;
  const int lm = ln & 15, qq = ln >> 4;
  const int bm = blockIdx.x;
  const short* Xb = oc + (size_t)bm * 32 * 256;
  floatx4 acc[2][4] = {};

  for (int k0 = 0; k0 < 4; ++k0) {
    __syncthreads();
    {
      const int row = tid >> 3, cg = tid & 7;
      const short8 s = *(const short8*)(Xb + (size_t)row * 256 + k0 * 64 + cg * 8);
      *(short8*)(Xs + row * 80 + (cg ^ (row & 7)) * 8) = s;
    }
    __syncthreads();
#pragma unroll
    for (int ks = 0; ks < 2; ++ks) {
      const int kblk = k0 * 2 + ks;
      short8 a[2], b[4];
#pragma unroll
      for (int mt = 0; mt < 2; ++mt) {
        const int row = mt * 16 + lm;
        a[mt] = *(const short8*)(Xs + row * 80 + (((ks * 4 + qq)) ^ (row & 7)) * 8);
      }
#pragma unroll
      for (int nt = 0; nt < 4; ++nt)
        b[nt] = *(const short8*)(Wf + ((size_t)(kblk * 16 + w * 4 + nt) * 64 + ln) * 8);
#pragma unroll
      for (int mt = 0; mt < 2; ++mt)
#pragma unroll
        for (int nt = 0; nt < 4; ++nt)
          acc[mt][nt] = __builtin_amdgcn_mfma_f32_16x16x32_bf16(a[mt], b[nt], acc[mt][nt], 0, 0, 0);
    }
  }
#pragma unroll
  for (int mt = 0; mt < 2; ++mt)
#pragma unroll
    for (int nt = 0; nt < 4; ++nt) {
      const int n = w * 64 + nt * 16 + lm;
      const float bval = bo[n];
      const int m0 = bm * 32 + mt * 16 + qq * 4;
#pragma unroll
      for (int r = 0; r < 4; ++r)
        __builtin_nontemporal_store(acc[mt][nt][r] + bval, out + (size_t)(m0 + r) * 256 + n);
    }
}

// ======================= fused attention ===================================
// phase2 v7 = v4 (proven best) + three strict slot cuts:
//  - diag mask applied ONCE on t (-inf) in pass A: 2^(-inf)=0 and
//    -inf*eff=-inf flow exactly through both passes (no pass-B cndmask).
//  - no 1e-5 clamp on eff (binds only for |gamma|>0.36; even then the
//    relative change in x is ~3e-5, far below tolerance).
//  - pos pre-multiplied by gsq: eff = 2^(-sqrt(gsq*tail*pos)), removing
//    the g*dist mul; the negate rides the exp2 input modifier.
template <int NP>
DEV void phase2(short* ss, float* shead, int row0, int w, int ln, float gsq) {
  const int c0 = ln * 4;
  for (int rr = 0; rr < 4; ++rr) {
    const int m = w * 4 + rr;
    const int irow = row0 + m;
    short* srow = ss + m * SST;

    float sv[NP * 4], e[NP * 4], ls[NP];

    // pass A: load t (= score*log2e) from fp16 LDS; diag-mask t to -inf;
    // e = 2^t; per-lane chunk sums.
#pragma unroll
    for (int p = 0; p < NP; ++p) {
      const uint2 u = *(const uint2*)(srow + p * 256 + c0);
      const float2 f0 = __half22float2(*(const __half2*)&u.x);
      const float2 f1 = __half22float2(*(const __half2*)&u.y);
      float t0 = f0.x, t1 = f0.y, t2 = f1.x, t3 = f1.y;
      if (p == NP - 1) {  // only diagonal chunk can be masked
        const int cb = p * 256 + c0;
        t0 = (cb + 0 <= irow) ? t0 : -INFINITY;
        t1 = (cb + 1 <= irow) ? t1 : -INFINITY;
        t2 = (cb + 2 <= irow) ? t2 : -INFINITY;
        t3 = (cb + 3 <= irow) ? t3 : -INFINITY;
      }
      sv[p * 4 + 0] = t0; sv[p * 4 + 1] = t1;
      sv[p * 4 + 2] = t2; sv[p * 4 + 3] = t3;
      e[p * 4 + 0] = ex2(t0); e[p * 4 + 1] = ex2(t1);
      e[p * 4 + 2] = ex2(t2); e[p * 4 + 3] = ex2(t3);
      ls[p] = (e[p * 4 + 0] + e[p * 4 + 1]) + (e[p * 4 + 2] + e[p * 4 + 3]);
    }

    // NP independent wave-scans in lockstep, then serial prefix of totals.
    float incl[NP];
#pragma unroll
    for (int p = 0; p < NP; ++p) incl[p] = ls[p];
#pragma unroll
    for (int off = 1; off < 64; off <<= 1) {
#pragma unroll
      for (int p = 0; p < NP; ++p) {
        const float y = __shfl_up(incl[p], off, 64);
        if (ln >= off) incl[p] += y;
      }
    }
    float excl[NP], Z = 0.f;
#pragma unroll
    for (int p = 0; p < NP; ++p) {
      excl[p] = Z + incl[p] - ls[p];
      Z += __shfl(incl[p], 63, 64);
    }
    const float invZ = 1.f / Z;

    // pass B: distance decay + second (unnormalized) softmax numerator.
    float ls2 = 0.f;
#pragma unroll
    for (int p = 0; p < NP; ++p) {
      float cum = excl[p];
      // pos' = gsq * (irow - c), maintained incrementally
      float pos = gsq * (float)(irow - (p * 256 + c0));
#pragma unroll
      for (int j = 0; j < 4; ++j) {
        cum += e[p * 4 + j];
        const float tail = 1.f - cum * invZ;      // (Z-cum)/Z
        const float d = sqrtf(__builtin_fabsf(tail * pos));
        const float eff = ex2(-d);                // 2^(g*dist), <= 1
        const float x = ex2(sv[p * 4 + j] * eff); // -inf -> 0 on masked
        e[p * 4 + j] = x;
        ls2 += x;
        pos -= gsq;
      }
    }
    const float i2 = 1.f / wsum(ls2);

    float* grow = shead + (size_t)irow * Ssz;
#pragma unroll
    for (int p = 0; p < NP; ++p) {
      floatx4 o;
      o.x = e[p * 4 + 0] * i2; o.y = e[p * 4 + 1] * i2;
      o.z = e[p * 4 + 2] * i2; o.w = e[p * 4 + 3] * i2;
      __builtin_nontemporal_store(o, (floatx4*)(grow + p * 256 + c0));
      uint2 pk;
      pk.x = bfpk(o.x, o.y);
      pk.y = bfpk(o.z, o.w);
      *(uint2*)(srow + p * 256 + c0) = pk;
    }
  }
}

__global__ __launch_bounds__(256, 4) void attn_kernel(
    const short* __restrict__ qh, const short* __restrict__ kh,
    const short* __restrict__ vt, const float* __restrict__ gammas,
    float* __restrict__ scores_out, short* __restrict__ oc) {
  __shared__ short ss[16 * SST];

  const int tid = threadIdx.x, ln = tid & 63, w = tid >> 6;
  const int lm = ln & 15, qq = ln >> 4;
  const int bh = blockIdx.x >> 6;
  const int row0 = (63 - (blockIdx.x & 63)) << 4;  // heavy tiles first
  const int h = bh & 7, b = bh >> 3;
  // scale * log2(e): LDS scores hold t = s*log2e so exps are raw v_exp_f32
  const float scaleL2e = 0.17677669529663687f * 1.4426950408889634f;
  const float g2 = -fabsf(gammas[h]) * 1.4426950408889634f;
  const float gsq = g2 * g2;  // eff = 2^(-sqrt(gsq*tail*pos))

  const short* qhead = qh + (size_t)bh * Ssz * DHn;
  const short* khead = kh + (size_t)bh * Ssz * DHn;
  const short* vhead = vt + (size_t)bh * DHn * Ssz;
  float* shead = scores_out + ((size_t)bh << 20);

  const short8 qa = *(const short8*)(qhead + (row0 + lm) * DHn + qq * 8);

  // phase 1: QK^T -> fp16 t-values in LDS (causal tiles only)
  const int ntile = (row0 >> 4) + 1;
  for (int t = w; t < ntile; t += 4) {
    const int n0 = t * 16;
    const short8 kb = *(const short8*)(khead + (n0 + lm) * DHn + qq * 8);
    floatx4 c = {0.f, 0.f, 0.f, 0.f};
    c = __builtin_amdgcn_mfma_f32_16x16x32_bf16(qa, kb, c, 0, 0, 0);
#pragma unroll
    for (int r = 0; r < 4; ++r)
      ss[(qq * 4 + r) * SST + n0 + lm] = f2h(c[r] * scaleL2e);
  }
  __syncthreads();

  // phase 2
  const int NPc = (row0 >> 8) + 1;
  switch (NPc) {
    case 1: phase2<1>(ss, shead, row0, w, ln, gsq); break;
    case 2: phase2<2>(ss, shead, row0, w, ln, gsq); break;
    case 3: phase2<3>(ss, shead, row0, w, ln, gsq); break;
    default: phase2<4>(ss, shead, row0, w, ln, gsq); break;
  }

  // zero-fill masked tail of scores rows (non-temporal)
  if (NPc < 4) {
    const floatx4 z4 = {0.f, 0.f, 0.f, 0.f};
    for (int r = 0; r < 16; ++r) {
      float* grow = shead + (size_t)(row0 + r) * Ssz + NPc * 256;
      for (int i = tid; i < (4 - NPc) * 64; i += 256)
        __builtin_nontemporal_store(z4, ((floatx4*)grow) + i);
    }
  }
  __syncthreads();

  // phase 3: PV via MFMA
  floatx4 o0 = {0.f, 0.f, 0.f, 0.f}, o1 = {0.f, 0.f, 0.f, 0.f};
  const int nkt = (row0 >> 5) + 1;
  for (int kt = w; kt < nkt; kt += 4) {
    const int k0 = kt * 32;
    const short8 av = *(const short8*)(ss + lm * SST + k0 + qq * 8);
    const short8 b0 = *(const short8*)(vhead + (lm << 10) + k0 + qq * 8);
    const short8 b1 = *(const short8*)(vhead + ((16 + lm) << 10) + k0 + qq * 8);
    o0 = __builtin_amdgcn_mfma_f32_16x16x32_bf16(av, b0, o0, 0, 0, 0);
    o1 = __builtin_amdgcn_mfma_f32_16x16x32_bf16(av, b1, o1, 0, 0, 0);
  }
  __syncthreads();
  float* red = (float*)ss;  // alias, 8 KB
#pragma unroll
  for (int r = 0; r < 4; ++r) {
    red[(w * 16 + qq * 4 + r) * 32 + lm] = o0[r];
    red[(w * 16 + qq * 4 + r) * 32 + 16 + lm] = o1[r];
  }
  __syncthreads();
  {
    const int m = tid >> 4, n = tid & 15;
    float a0 = 0.f, a1 = 0.f;
#pragma unroll
    for (int wv = 0; wv < 4; ++wv) {
      a0 += red[(wv * 16 + m) * 32 + n];
      a1 += red[(wv * 16 + m) * 32 + 16 + n];
    }
    const size_t row = ((size_t)b << 10) + row0 + m;
    oc[row * Dsz + h * DHn + n] = f2bf(a0);
    oc[row * Dsz + h * DHn + 16 + n] = f2bf(a1);
  }
}

// ---------------- launch ---------------------------------------------------
extern "C" void kernel_launch(void* const* d_in, const int* in_sizes, int n_in,
                              void* d_out, int out_size, void* d_ws, size_t ws_size,
                              hipStream_t stream) {
  const float* q  = (const float*)d_in[0];
  const float* k  = (const float*)d_in[1];
  const float* v  = (const float*)d_in[2];
  const float* Wq = (const float*)d_in[4];
  const float* bq = (const float*)d_in[5];
  const float* Wv = (const float*)d_in[6];
  const float* bv = (const float*)d_in[7];
  const float* Wo = (const float*)d_in[8];
  const float* bo = (const float*)d_in[9];
  const float* gm = (const float*)d_in[10];

  float* out    = (float*)d_out;                  // [B,S,D] fp32
  float* scores = out + (size_t)Bsz * Ssz * Dsz;  // [B,H,S,S] fp32

  const size_t Q = (size_t)Bsz * Hn * Ssz * DHn;
  short* qh = (short*)d_ws;        // bf16 [B,H,S,DH]
  short* kh = qh + Q;
  short* vt = kh + Q;              // bf16 [B,H,DH,S]
  short* oc = vt + Q;              // bf16 [B,S,D]
  short* Wf = oc + Q;              // bf16 frag-order weights, 3 x 65536

  const dim3 blk(256);
  hipLaunchKernelGGL(cvt_wfrag, dim3(32, 3), blk, 0, stream, Wq, Wv, Wo, Wf);
  hipLaunchKernelGGL(proj_qkv2, dim3(256, 3), blk, 0, stream,
                     q, k, v, Wf, bq, bv, qh, kh, vt);
  hipLaunchKernelGGL(attn_kernel, dim3(Bsz * Hn * (Ssz / 16)), blk, 0, stream,
                     qh, kh, vt, gm, scores, oc);
  hipLaunchKernelGGL(proj_out2, dim3(256), blk, 0, stream, oc, Wf, bo, out);
}

// Round 7
// 357.288 us; speedup vs baseline: 1.0102x; 1.0029x over previous
//
#include <hip/hip_runtime.h>
#include <hip/hip_fp16.h>
#include <math.h>

// B=8, S=1024, D=256, H=8, DH=32
constexpr int Bsz = 8, Ssz = 1024, Dsz = 256, Hn = 8, DHn = 32;
// attn LDS: 16 x 1024 fp16 = 32 KB exactly -> 5 blocks/CU (160 KB).
// Bank conflicts broken by XOR swizzle col ^= (row&7)<<3 (8-short granule).
constexpr int SST = 1024;

typedef __attribute__((ext_vector_type(8))) short short8;
typedef __attribute__((ext_vector_type(4))) float floatx4;

#define DEV static __device__ __forceinline__

DEV short f2bf(float f) {  // fp32 -> bf16 RNE
  union { float f; unsigned u; } x; x.f = f;
  return (short)((x.u + 0x7fffu + ((x.u >> 16) & 1u)) >> 16);
}
DEV short f2h(float f) {
  __half h = __float2half(f);
  return *(short*)&h;
}
DEV unsigned bfpk(float lo, float hi) {  // v_cvt_pk_bf16_f32: {hi,lo} -> 2xbf16
  unsigned r;
  asm("v_cvt_pk_bf16_f32 %0, %1, %2" : "=v"(r) : "v"(lo), "v"(hi));
  return r;
}
DEV float ex2(float x) {  // raw v_exp_f32 (2^x)
#if __has_builtin(__builtin_amdgcn_exp2f)
  return __builtin_amdgcn_exp2f(x);
#else
  return __expf(x * 0.69314718055994531f);
#endif
}
DEV float wsum(float v) {
#pragma unroll
  for (int off = 32; off > 0; off >>= 1) v += __shfl_xor(v, off, 64);
  return v;
}

// ============ W pre-convert: fp32 row-major -> bf16 MFMA B-frag order =======
// layout: [kblk(8)][ntile(16)][lane(64)][8 bf16]; element =
//   W[ntile*16 + (lane&15)][kblk*32 + (lane>>4)*8 + j]
__global__ __launch_bounds__(256) void cvt_wfrag(const float* __restrict__ Wq,
                                                 const float* __restrict__ Wv,
                                                 const float* __restrict__ Wo,
                                                 short* __restrict__ dst) {
  const int which = blockIdx.y;
  const float* W = (which == 0) ? Wq : (which == 1) ? Wv : Wo;
  const int t = blockIdx.x * 256 + threadIdx.x;  // 0..8191
  const int ln = t & 63, nt = (t >> 6) & 15, kblk = t >> 10;
  const float* src = W + (size_t)(nt * 16 + (ln & 15)) * 256 + kblk * 32 + (ln >> 4) * 8;
  const float4 a = *(const float4*)src;
  const float4 b = *(const float4*)(src + 4);
  const float tmp[8] = {a.x, a.y, a.z, a.w, b.x, b.y, b.z, b.w};
  short8 s;
#pragma unroll
  for (int j = 0; j < 8; ++j) s[j] = f2bf(tmp[j]);
  *(short8*)(dst + ((size_t)which << 16) + (size_t)t * 8) = s;
}

// ============ projections: 32 rows x full N=256 per block ==================
// Xs: 32x80 bf16, granule-XOR swizzled. Wave w owns n-range [w*64, w*64+64).
__global__ __launch_bounds__(256, 4) void proj_qkv2(
    const float* __restrict__ qi, const float* __restrict__ ki, const float* __restrict__ vi,
    const short* __restrict__ Wfrag, const float* __restrict__ bq, const float* __restrict__ bv,
    short* __restrict__ qh, short* __restrict__ kh, short* __restrict__ vt) {
  __shared__ short Xs[32 * 80];
  const int which = blockIdx.y;
  const float* X = (which == 0) ? qi : (which == 1) ? ki : vi;
  const short* Wf = Wfrag + ((which == 2) ? (1 << 16) : 0);
  const float* bias = (which == 2) ? bv : bq;
  const int tid = threadIdx.x, ln = tid & 63, w = tid >> 6;
  const int lm = ln & 15, qq = ln >> 4;
  const int bm = blockIdx.x;  // 256 blocks of 32 rows
  const float* Xb = X + (size_t)bm * 32 * 256;
  floatx4 acc[2][4] = {};

  for (int k0 = 0; k0 < 4; ++k0) {
    __syncthreads();
    {
      const int row = tid >> 3, cg = tid & 7;
#pragma unroll
      for (int i = 0; i < 2; ++i) {
        const float4 f = *(const float4*)(Xb + (size_t)row * 256 + k0 * 64 + cg * 8 + i * 4);
        short4 s; s.x = f2bf(f.x); s.y = f2bf(f.y); s.z = f2bf(f.z); s.w = f2bf(f.w);
        *(short4*)(Xs + row * 80 + (cg ^ (row & 7)) * 8 + i * 4) = s;
      }
    }
    __syncthreads();
#pragma unroll
    for (int ks = 0; ks < 2; ++ks) {
      const int kblk = k0 * 2 + ks;
      short8 a[2], b[4];
#pragma unroll
      for (int mt = 0; mt < 2; ++mt) {
        const int row = mt * 16 + lm;
        a[mt] = *(const short8*)(Xs + row * 80 + (((ks * 4 + qq)) ^ (row & 7)) * 8);
      }
#pragma unroll
      for (int nt = 0; nt < 4; ++nt)
        b[nt] = *(const short8*)(Wf + ((size_t)(kblk * 16 + w * 4 + nt) * 64 + ln) * 8);
#pragma unroll
      for (int mt = 0; mt < 2; ++mt)
#pragma unroll
        for (int nt = 0; nt < 4; ++nt)
          acc[mt][nt] = __builtin_amdgcn_mfma_f32_16x16x32_bf16(a[mt], b[nt], acc[mt][nt], 0, 0, 0);
    }
  }

#pragma unroll
  for (int mt = 0; mt < 2; ++mt) {
#pragma unroll
    for (int nt = 0; nt < 4; ++nt) {
      const int n = w * 64 + nt * 16 + lm;
      const float bval = bias[n];
      const int m0 = bm * 32 + mt * 16 + qq * 4;
      const int h = n >> 5, dh = n & 31;
      if (which <= 1) {  // head-split [B,H,S,DH]
        short* dst = (which == 0) ? qh : kh;
#pragma unroll
        for (int r = 0; r < 4; ++r) {
          const int m = m0 + r, b_ = m >> 10, s = m & 1023;
          dst[(((size_t)(b_ * Hn + h) << 10) + s) * DHn + dh] = f2bf(acc[mt][nt][r] + bval);
        }
      } else {  // V^T [B,H,DH,S]
        const int b_ = m0 >> 10, s0 = m0 & 1023;
        short4 pk;
        pk.x = f2bf(acc[mt][nt][0] + bval);
        pk.y = f2bf(acc[mt][nt][1] + bval);
        pk.z = f2bf(acc[mt][nt][2] + bval);
        pk.w = f2bf(acc[mt][nt][3] + bval);
        *(short4*)(vt + ((size_t)((b_ * Hn + h) * DHn + dh) << 10) + s0) = pk;
      }
    }
  }
}

__global__ __launch_bounds__(256, 4) void proj_out2(
    const short* __restrict__ oc, const short* __restrict__ Wfrag,
    const float* __restrict__ bo, float* __restrict__ out) {
  __shared__ short Xs[32 * 80];
  const short* Wf = Wfrag + (2 << 16);
  const int tid = threadIdx.x, ln = tid & 63, w = tid >> 6;
  const int lm = ln & 15, qq = ln >> 4;
  const int bm = blockIdx.x;
  const short* Xb = oc + (size_t)bm * 32 * 256;
  floatx4 acc[2][4] = {};

  for (int k0 = 0; k0 < 4; ++k0) {
    __syncthreads();
    {
      const int row = tid >> 3, cg = tid & 7;
      const short8 s = *(const short8*)(Xb + (size_t)row * 256 + k0 * 64 + cg * 8);
      *(short8*)(Xs + row * 80 + (cg ^ (row & 7)) * 8) = s;
    }
    __syncthreads();
#pragma unroll
    for (int ks = 0; ks < 2; ++ks) {
      const int kblk = k0 * 2 + ks;
      short8 a[2], b[4];
#pragma unroll
      for (int mt = 0; mt < 2; ++mt) {
        const int row = mt * 16 + lm;
        a[mt] = *(const short8*)(Xs + row * 80 + (((ks * 4 + qq)) ^ (row & 7)) * 8);
      }
#pragma unroll
      for (int nt = 0; nt < 4; ++nt)
        b[nt] = *(const short8*)(Wf + ((size_t)(kblk * 16 + w * 4 + nt) * 64 + ln) * 8);
#pragma unroll
      for (int mt = 0; mt < 2; ++mt)
#pragma unroll
        for (int nt = 0; nt < 4; ++nt)
          acc[mt][nt] = __builtin_amdgcn_mfma_f32_16x16x32_bf16(a[mt], b[nt], acc[mt][nt], 0, 0, 0);
    }
  }
#pragma unroll
  for (int mt = 0; mt < 2; ++mt)
#pragma unroll
    for (int nt = 0; nt < 4; ++nt) {
      const int n = w * 64 + nt * 16 + lm;
      const float bval = bo[n];
      const int m0 = bm * 32 + mt * 16 + qq * 4;
#pragma unroll
      for (int r = 0; r < 4; ++r)
        __builtin_nontemporal_store(acc[mt][nt][r] + bval, out + (size_t)(m0 + r) * 256 + n);
    }
}

// ======================= fused attention ===================================
// phase2 v8 = v7 body (proven-equal, strictly fewer slots) on SST=1024 with
// row-XOR swizzle. Key point vs failed R4: the swizzle XOR is ROW-CONSTANT
// in phase2 and folds into a precomputed c0x (c0 bits 2-7, X bits 3-5,
// p*256 bits >=8) -> zero added instructions on the hot path; sv stays in
// registers (no pass-B LDS reload).
template <int NP>
DEV void phase2(short* ss, float* shead, int row0, int w, int ln, float gsq) {
  const int c0 = ln * 4;
  for (int rr = 0; rr < 4; ++rr) {
    const int m = w * 4 + rr;
    const int irow = row0 + m;
    short* srow = ss + m * SST;
    const int c0x = c0 ^ ((m & 7) << 3);  // swizzled lane base, row-constant

    float sv[NP * 4], e[NP * 4], ls[NP];

    // pass A: load t (= score*log2e) from fp16 LDS; diag-mask t to -inf;
    // e = 2^t; per-lane chunk sums.
#pragma unroll
    for (int p = 0; p < NP; ++p) {
      const uint2 u = *(const uint2*)(srow + p * 256 + c0x);
      const float2 f0 = __half22float2(*(const __half2*)&u.x);
      const float2 f1 = __half22float2(*(const __half2*)&u.y);
      float t0 = f0.x, t1 = f0.y, t2 = f1.x, t3 = f1.y;
      if (p == NP - 1) {  // only diagonal chunk can be masked (logical col!)
        const int cb = p * 256 + c0;
        t0 = (cb + 0 <= irow) ? t0 : -INFINITY;
        t1 = (cb + 1 <= irow) ? t1 : -INFINITY;
        t2 = (cb + 2 <= irow) ? t2 : -INFINITY;
        t3 = (cb + 3 <= irow) ? t3 : -INFINITY;
      }
      sv[p * 4 + 0] = t0; sv[p * 4 + 1] = t1;
      sv[p * 4 + 2] = t2; sv[p * 4 + 3] = t3;
      e[p * 4 + 0] = ex2(t0); e[p * 4 + 1] = ex2(t1);
      e[p * 4 + 2] = ex2(t2); e[p * 4 + 3] = ex2(t3);
      ls[p] = (e[p * 4 + 0] + e[p * 4 + 1]) + (e[p * 4 + 2] + e[p * 4 + 3]);
    }

    // NP independent wave-scans in lockstep, then serial prefix of totals.
    float incl[NP];
#pragma unroll
    for (int p = 0; p < NP; ++p) incl[p] = ls[p];
#pragma unroll
    for (int off = 1; off < 64; off <<= 1) {
#pragma unroll
      for (int p = 0; p < NP; ++p) {
        const float y = __shfl_up(incl[p], off, 64);
        if (ln >= off) incl[p] += y;
      }
    }
    float excl[NP], Z = 0.f;
#pragma unroll
    for (int p = 0; p < NP; ++p) {
      excl[p] = Z + incl[p] - ls[p];
      Z += __shfl(incl[p], 63, 64);
    }
    const float invZ = 1.f / Z;

    // pass B: distance decay + second (unnormalized) softmax numerator.
    float ls2 = 0.f;
#pragma unroll
    for (int p = 0; p < NP; ++p) {
      float cum = excl[p];
      // pos' = gsq * (irow - c), maintained incrementally
      float pos = gsq * (float)(irow - (p * 256 + c0));
#pragma unroll
      for (int j = 0; j < 4; ++j) {
        cum += e[p * 4 + j];
        const float tail = 1.f - cum * invZ;      // (Z-cum)/Z
        const float d = sqrtf(__builtin_fabsf(tail * pos));
        const float eff = ex2(-d);                // 2^(g*dist), <= 1
        const float x = ex2(sv[p * 4 + j] * eff); // -inf -> 0 on masked
        e[p * 4 + j] = x;
        ls2 += x;
        pos -= gsq;
      }
    }
    const float i2 = 1.f / wsum(ls2);

    float* grow = shead + (size_t)irow * Ssz;
#pragma unroll
    for (int p = 0; p < NP; ++p) {
      floatx4 o;
      o.x = e[p * 4 + 0] * i2; o.y = e[p * 4 + 1] * i2;
      o.z = e[p * 4 + 2] * i2; o.w = e[p * 4 + 3] * i2;
      __builtin_nontemporal_store(o, (floatx4*)(grow + p * 256 + c0));
      uint2 pk;
      pk.x = bfpk(o.x, o.y);
      pk.y = bfpk(o.z, o.w);
      *(uint2*)(srow + p * 256 + c0x) = pk;
    }
  }
}

__global__ __launch_bounds__(256, 5) void attn_kernel(
    const short* __restrict__ qh, const short* __restrict__ kh,
    const short* __restrict__ vt, const float* __restrict__ gammas,
    float* __restrict__ scores_out, short* __restrict__ oc) {
  __shared__ short ss[16 * SST];  // 32 KB exactly -> 5 blocks/CU

  const int tid = threadIdx.x, ln = tid & 63, w = tid >> 6;
  const int lm = ln & 15, qq = ln >> 4;
  const int bh = blockIdx.x >> 6;
  const int row0 = (63 - (blockIdx.x & 63)) << 4;  // heavy tiles first
  const int h = bh & 7, b = bh >> 3;
  // scale * log2(e): LDS scores hold t = s*log2e so exps are raw v_exp_f32
  const float scaleL2e = 0.17677669529663687f * 1.4426950408889634f;
  const float g2 = -fabsf(gammas[h]) * 1.4426950408889634f;
  const float gsq = g2 * g2;  // eff = 2^(-sqrt(gsq*tail*pos))

  const short* qhead = qh + (size_t)bh * Ssz * DHn;
  const short* khead = kh + (size_t)bh * Ssz * DHn;
  const short* vhead = vt + (size_t)bh * DHn * Ssz;
  float* shead = scores_out + ((size_t)bh << 20);

  const short8 qa = *(const short8*)(qhead + (row0 + lm) * DHn + qq * 8);

  // phase 1: QK^T -> fp16 t-values in LDS (causal tiles only)
  const int ntile = (row0 >> 4) + 1;
  for (int t = w; t < ntile; t += 4) {
    const int n0 = t * 16;
    const short8 kb = *(const short8*)(khead + (n0 + lm) * DHn + qq * 8);
    floatx4 c = {0.f, 0.f, 0.f, 0.f};
    c = __builtin_amdgcn_mfma_f32_16x16x32_bf16(qa, kb, c, 0, 0, 0);
#pragma unroll
    for (int r = 0; r < 4; ++r) {
      const int row = qq * 4 + r;
      ss[row * SST + ((n0 + lm) ^ ((row & 7) << 3))] = f2h(c[r] * scaleL2e);
    }
  }
  __syncthreads();

  // phase 2
  const int NPc = (row0 >> 8) + 1;
  switch (NPc) {
    case 1: phase2<1>(ss, shead, row0, w, ln, gsq); break;
    case 2: phase2<2>(ss, shead, row0, w, ln, gsq); break;
    case 3: phase2<3>(ss, shead, row0, w, ln, gsq); break;
    default: phase2<4>(ss, shead, row0, w, ln, gsq); break;
  }

  // zero-fill masked tail of scores rows (non-temporal)
  if (NPc < 4) {
    const floatx4 z4 = {0.f, 0.f, 0.f, 0.f};
    for (int r = 0; r < 16; ++r) {
      float* grow = shead + (size_t)(row0 + r) * Ssz + NPc * 256;
      for (int i = tid; i < (4 - NPc) * 64; i += 256)
        __builtin_nontemporal_store(z4, ((floatx4*)grow) + i);
    }
  }
  __syncthreads();

  // phase 3: PV via MFMA (swizzled LDS read: 1 extra XOR per load)
  floatx4 o0 = {0.f, 0.f, 0.f, 0.f}, o1 = {0.f, 0.f, 0.f, 0.f};
  const int nkt = (row0 >> 5) + 1;
  const int xlm = (lm & 7) << 3;
  for (int kt = w; kt < nkt; kt += 4) {
    const int k0 = kt * 32;
    const short8 av = *(const short8*)(ss + lm * SST + ((k0 + qq * 8) ^ xlm));
    const short8 b0 = *(const short8*)(vhead + (lm << 10) + k0 + qq * 8);
    const short8 b1 = *(const short8*)(vhead + ((16 + lm) << 10) + k0 + qq * 8);
    o0 = __builtin_amdgcn_mfma_f32_16x16x32_bf16(av, b0, o0, 0, 0, 0);
    o1 = __builtin_amdgcn_mfma_f32_16x16x32_bf16(av, b1, o1, 0, 0, 0);
  }
  __syncthreads();
  float* red = (float*)ss;  // alias, 8 KB
#pragma unroll
  for (int r = 0; r < 4; ++r) {
    red[(w * 16 + qq * 4 + r) * 32 + lm] = o0[r];
    red[(w * 16 + qq * 4 + r) * 32 + 16 + lm] = o1[r];
  }
  __syncthreads();
  {
    const int m = tid >> 4, n = tid & 15;
    float a0 = 0.f, a1 = 0.f;
#pragma unroll
    for (int wv = 0; wv < 4; ++wv) {
      a0 += red[(wv * 16 + m) * 32 + n];
      a1 += red[(wv * 16 + m) * 32 + 16 + n];
    }
    const size_t row = ((size_t)b << 10) + row0 + m;
    oc[row * Dsz + h * DHn + n] = f2bf(a0);
    oc[row * Dsz + h * DHn + 16 + n] = f2bf(a1);
  }
}

// ---------------- launch ---------------------------------------------------
extern "C" void kernel_launch(void* const* d_in, const int* in_sizes, int n_in,
                              void* d_out, int out_size, void* d_ws, size_t ws_size,
                              hipStream_t stream) {
  const float* q  = (const float*)d_in[0];
  const float* k  = (const float*)d_in[1];
  const float* v  = (const float*)d_in[2];
  const float* Wq = (const float*)d_in[4];
  const float* bq = (const float*)d_in[5];
  const float* Wv = (const float*)d_in[6];
  const float* bv = (const float*)d_in[7];
  const float* Wo = (const float*)d_in[8];
  const float* bo = (const float*)d_in[9];
  const float* gm = (const float*)d_in[10];

  float* out    = (float*)d_out;                  // [B,S,D] fp32
  float* scores = out + (size_t)Bsz * Ssz * Dsz;  // [B,H,S,S] fp32

  const size_t Q = (size_t)Bsz * Hn * Ssz * DHn;
  short* qh = (short*)d_ws;        // bf16 [B,H,S,DH]
  short* kh = qh + Q;
  short* vt = kh + Q;              // bf16 [B,H,DH,S]
  short* oc = vt + Q;              // bf16 [B,S,D]
  short* Wf = oc + Q;              // bf16 frag-order weights, 3 x 65536

  const dim3 blk(256);
  hipLaunchKernelGGL(cvt_wfrag, dim3(32, 3), blk, 0, stream, Wq, Wv, Wo, Wf);
  hipLaunchKernelGGL(proj_qkv2, dim3(256, 3), blk, 0, stream,
                     q, k, v, Wf, bq, bv, qh, kh, vt);
  hipLaunchKernelGGL(attn_kernel, dim3(Bsz * Hn * (Ssz / 16)), blk, 0, stream,
                     qh, kh, vt, gm, scores, oc);
  hipLaunchKernelGGL(proj_out2, dim3(256), blk, 0, stream, oc, Wf, bo, out);
}